// Round 12
// baseline (191.945 us; speedup 1.0000x reference)
//
#include <hip/hip_runtime.h>
#include <math.h>

// CapsLayer dynamic routing, MI355X fp32.
// x: [64, 2048, 8]  W: [2048, 32, 8, 16]  out: [64, 32, 16]
// Never materialize u_hat (256 MB); recompute per routing pass.
// R14: dispatch-count surgery. R13 ledger: route1 x2 = 86us; the OTHER
// ~104us was 8 small kernels + 10 launch gaps. Collapse 11 -> 6 dispatches:
//   - squash fused into route1 prologue: v reconstructed per-thread from raw
//     sum s via in-thread dot + 2 shfl_xor (the 4-lane e-group pattern) +
//     squash scale. Pass 2 loads s0 AND s1, two norms, v = v0+v1.
//   - reduce_p: 512-block exclusive-write (one block per (b, 64-out slice))
//     -> no atomics -> no zero_s. (R12: 256-way atomic fan-in serialized;
//     R13's 4-way+zero worked but cost dispatches.)
//   - final reduce_squash writes out directly.
// Sequence: route0, reduce_s(s0), route1<1>, reduce_s(s1), route1<2>,
// reduce_squash(out).
// route1 loop body = R5/R13's proven 43us kernel, untouched (6 structural
// variants all landed 43-48us; VALU-busy ~20us of 43 => body is near its
// floor). Spill law (R3/R4/R6/R8): #pragma unroll 1 on ii is load-bearing.
// Tripwires: absmax = 0.00098 (inline-squash numerics), route1 <= 50us,
// FETCH ~39 MB, VGPR <= 64.

#define B_TOT 64
#define I_TOT 2048
#define D_IN  8
#define NC    32
#define EV    16
#define OD    (NC*EV)      // 512 outputs per b
#define BC    8            // batch rows per block (softmax passes)
#define NBC   (B_TOT/BC)   // 8 b-chunks
#define BC0   16           // batch rows per block (pass-0 GEMM)
#define NBC0  (B_TOT/BC0)  // 4 b-chunks
#define ICH   8            // i's per block
#define NIC   (I_TOT/ICH)  // 256 i-chunks
#define S_ELEMS (B_TOT*OD) // 32768 floats = 128 KB per s-slice

__device__ __forceinline__ void fma4(float4& acc, float a, const float4& w) {
    acc.x = fmaf(a, w.x, acc.x);
    acc.y = fmaf(a, w.y, acc.y);
    acc.z = fmaf(a, w.z, acc.z);
    acc.w = fmaf(a, w.w, acc.w);
}

// ---- pass 0: c uniform. s0 = sum_i x[b,i,:] @ W[i] — a GEMM, no per-i u.
// BC0=16 rows/block: thread (eq,bh,n) folds wr[8] into 8 b-rows directly.
__global__ __launch_bounds__(256, 4)
void route0(const float* __restrict__ x, const float* __restrict__ W,
            float* __restrict__ P)
{
    __shared__ __align__(16) float xl[BC0 * ICH * D_IN];  // 4 KB

    const int t  = threadIdx.x;
    const int ic = blockIdx.x & (NIC - 1);   // 0..255 (blk%8==ic%8: XCD swz)
    const int bc = blockIdx.x >> 8;          // 0..3
    const int b0 = bc * BC0;
    const int i0 = ic * ICH;
    const int eq = t & 3;
    const int bh = (t >> 2) & 1;
    const int n  = t >> 3;

    // stage x[b0..b0+15][i0..i0+7][0..7] (4 KB): 256 float4, one per thread
    {
        const int row = t >> 4, f = (t & 15) * 4;
        *(float4*)&xl[row * (ICH * D_IN) + f] =
            *(const float4*)&x[((size_t)(b0 + row) * I_TOT + i0) * D_IN + f];
    }
    __syncthreads();

    float4 sacc[8];
    #pragma unroll
    for (int q = 0; q < 8; ++q) sacc[q] = make_float4(0.f, 0.f, 0.f, 0.f);

    const float* Wt = &W[(size_t)i0 * 4096 + n * 128 + eq * 4];

    // unroll 1 is load-bearing (spill law)
    #pragma unroll 1
    for (int ii = 0; ii < ICH; ++ii) {
        float4 wr[8];
        #pragma unroll
        for (int d = 0; d < 8; ++d)
            wr[d] = *(const float4*)&Wt[ii * 4096 + d * 16];

        #pragma unroll
        for (int q = 0; q < 8; ++q) {
            const int bl = bh * 8 + q;
            float4 xa = *(float4*)&xl[bl * (ICH * D_IN) + ii * 8];
            float4 xb = *(float4*)&xl[bl * (ICH * D_IN) + ii * 8 + 4];
            fma4(sacc[q], xa.x, wr[0]); fma4(sacc[q], xa.y, wr[1]);
            fma4(sacc[q], xa.z, wr[2]); fma4(sacc[q], xa.w, wr[3]);
            fma4(sacc[q], xb.x, wr[4]); fma4(sacc[q], xb.y, wr[5]);
            fma4(sacc[q], xb.z, wr[6]); fma4(sacc[q], xb.w, wr[7]);
        }
    }

    #pragma unroll
    for (int q = 0; q < 8; ++q)
        *(float4*)&P[((size_t)ic * B_TOT + b0 + bh * 8 + q) * OD + n * EV + eq * 4] = sacc[q];
}

// ---- passes 1/2: c = softmax_n(u . v). v is reconstructed in the prologue
// from the raw reduce sums: NS=1: v = squash(s0*pre0); NS=2: v = squash(s0*
// pre0) + squash(s1)  (iter-2 logits u.v0 + u.v1 = u.(v0+v1), dot linearity).
template <int NS>
__global__ __launch_bounds__(256, 4)
void route1(const float* __restrict__ x, const float* __restrict__ W,
            float* __restrict__ P, const float* __restrict__ s0,
            const float* __restrict__ s1, float pre0)
{
    __shared__ __align__(16) float xl[BC * ICH * D_IN];   // 2 KB
    __shared__ float wsum[2][4][BC];                      // 256 B (ii-dbuf)

    const int t  = threadIdx.x;
    const int ic = blockIdx.x & (NIC - 1);   // 0..255 (blk%8==ic%8: XCD swz)
    const int bc = blockIdx.x >> 8;          // 0..7
    const int b0 = bc * BC;
    const int i0 = ic * ICH;
    const int eq = t & 3;          // e quarter (4 e's)
    const int bh = (t >> 2) & 1;   // b half (4 b's each)
    const int n  = t >> 3;         // capsule 0..31
    const int w  = t >> 6;         // wave 0..3

    if (t < 128) {
        const int row = t >> 4, f = (t & 15) * 4;
        *(float4*)&xl[row * (ICH * D_IN) + f] =
            *(const float4*)&x[((size_t)(b0 + row) * I_TOT + i0) * D_IN + f];
    }

    // ---- inline squash: vr[q] = v[b0+bh*4+q][n][eq*4..+3] ----
    // norm over the 16 e's of (b,n): in-thread dot of 4 + shfl over eq bits.
    float4 vr[4];
    #pragma unroll
    for (int q = 0; q < 4; ++q) {
        const size_t off = (size_t)(b0 + bh * 4 + q) * OD + n * EV + eq * 4;
        float4 t0 = *(const float4*)&s0[off];
        t0.x *= pre0; t0.y *= pre0; t0.z *= pre0; t0.w *= pre0;
        float q2 = t0.x*t0.x + t0.y*t0.y + t0.z*t0.z + t0.w*t0.w;
        q2 += __shfl_xor(q2, 1, 64);
        q2 += __shfl_xor(q2, 2, 64);
        float sc = q2 / ((1.0f + q2) * sqrtf(q2));
        float4 v = make_float4(t0.x*sc, t0.y*sc, t0.z*sc, t0.w*sc);
        if (NS == 2) {
            float4 t1 = *(const float4*)&s1[off];
            float r2 = t1.x*t1.x + t1.y*t1.y + t1.z*t1.z + t1.w*t1.w;
            r2 += __shfl_xor(r2, 1, 64);
            r2 += __shfl_xor(r2, 2, 64);
            float sc1 = r2 / ((1.0f + r2) * sqrtf(r2));
            v.x = fmaf(t1.x, sc1, v.x); v.y = fmaf(t1.y, sc1, v.y);
            v.z = fmaf(t1.z, sc1, v.z); v.w = fmaf(t1.w, sc1, v.w);
        }
        vr[q] = v;
    }
    __syncthreads();

    float4 sacc[4];
    #pragma unroll
    for (int q = 0; q < 4; ++q) sacc[q] = make_float4(0.f, 0.f, 0.f, 0.f);

    const float* Wt = &W[(size_t)i0 * 4096 + n * 128 + eq * 4];

    // unroll 1 is load-bearing (spill law: R3/R4 hoist -> 1.1 GB scratch)
    #pragma unroll 1
    for (int ii = 0; ii < ICH; ++ii) {
        float4 wr[8];
        #pragma unroll
        for (int d = 0; d < 8; ++d)
            wr[d] = *(const float4*)&Wt[ii * 4096 + d * 16];

        float4 u[4];
        #pragma unroll
        for (int q = 0; q < 4; ++q) {
            const int bl = bh * 4 + q;
            float4 xa = *(float4*)&xl[bl * (ICH * D_IN) + ii * 8];
            float4 xb = *(float4*)&xl[bl * (ICH * D_IN) + ii * 8 + 4];
            float4 uu = make_float4(0.f, 0.f, 0.f, 0.f);
            fma4(uu, xa.x, wr[0]); fma4(uu, xa.y, wr[1]);
            fma4(uu, xa.z, wr[2]); fma4(uu, xa.w, wr[3]);
            fma4(uu, xb.x, wr[4]); fma4(uu, xb.y, wr[5]);
            fma4(uu, xb.z, wr[6]); fma4(uu, xb.w, wr[7]);
            u[q] = uu;
        }

        float a[4];
        #pragma unroll
        for (int q = 0; q < 4; ++q) {
            float ap = u[q].x * vr[q].x + u[q].y * vr[q].y
                     + u[q].z * vr[q].z + u[q].w * vr[q].w;
            ap += __shfl_xor(ap, 1, 64);
            ap += __shfl_xor(ap, 2, 64);
            a[q] = ap;
        }
        float e[4], p[4];
        #pragma unroll
        for (int q = 0; q < 4; ++q) {
            e[q] = __expf(a[q]);
            float pp = e[q];
            pp += __shfl_xor(pp, 8, 64);
            pp += __shfl_xor(pp, 16, 64);
            pp += __shfl_xor(pp, 32, 64);
            p[q] = pp;
        }
        if (eq == 0) {
            #pragma unroll
            for (int q = 0; q < 4; ++q)
                wsum[ii & 1][w][bh * 4 + q] = p[q];
        }
        __syncthreads();
        #pragma unroll
        for (int q = 0; q < 4; ++q) {
            const int bl = bh * 4 + q;
            float s = wsum[ii & 1][0][bl] + wsum[ii & 1][1][bl]
                    + wsum[ii & 1][2][bl] + wsum[ii & 1][3][bl];
            float c = __fdividef(e[q], s);
            fma4(sacc[q], c, u[q]);
        }
    }

    #pragma unroll
    for (int q = 0; q < 4; ++q)
        *(float4*)&P[((size_t)ic * B_TOT + b0 + bh * 4 + q) * OD + n * EV + eq * 4] = sacc[q];
}

// ---- reduce P over 256 i-chunks into s[b][o]. 512 blocks (b x 8 o-slices),
// exclusive writes (no atomics, no zeroing). 256 thr = 64 o x 4 ic-quarters.
__global__ __launch_bounds__(256, 4)
void reduce_s(const float* __restrict__ P, float* __restrict__ s)
{
    __shared__ float red[256];
    const int b   = blockIdx.x >> 3;
    const int oq  = blockIdx.x & 7;
    const int t   = threadIdx.x;
    const int o   = oq * 64 + (t & 63);
    const int icq = t >> 6;                       // 0..3
    const size_t stride = (size_t)B_TOT * OD;

    float acc = 0.f;
    size_t base = ((size_t)(icq * 64) * B_TOT + b) * OD + o;
    #pragma unroll 8
    for (int k = 0; k < 64; ++k) acc += P[base + (size_t)k * stride];
    red[t] = acc;
    __syncthreads();
    if (t < 64)
        s[(size_t)b * OD + o] = red[t] + red[t + 64] + red[t + 128] + red[t + 192];
}

// ---- final: reduce P over ic then squash, straight into out. 512 blocks.
__global__ __launch_bounds__(256, 4)
void reduce_squash(const float* __restrict__ P, float* __restrict__ dst)
{
    __shared__ float red[256];
    const int b   = blockIdx.x >> 3;
    const int oq  = blockIdx.x & 7;
    const int t   = threadIdx.x;
    const int o   = oq * 64 + (t & 63);
    const int icq = t >> 6;
    const size_t stride = (size_t)B_TOT * OD;

    float acc = 0.f;
    size_t base = ((size_t)(icq * 64) * B_TOT + b) * OD + o;
    #pragma unroll 8
    for (int k = 0; k < 64; ++k) acc += P[base + (size_t)k * stride];
    red[t] = acc;
    __syncthreads();

    if (t < 64) {
        float v = red[t] + red[t + 64] + red[t + 128] + red[t + 192];
        float q2 = v * v;
        q2 += __shfl_xor(q2, 1, 64);
        q2 += __shfl_xor(q2, 2, 64);
        q2 += __shfl_xor(q2, 4, 64);
        q2 += __shfl_xor(q2, 8, 64);
        float sc = q2 / ((1.0f + q2) * sqrtf(q2));
        dst[(size_t)b * OD + o] = v * sc;
    }
}

extern "C" void kernel_launch(void* const* d_in, const int* in_sizes, int n_in,
                              void* d_out, int out_size, void* d_ws, size_t ws_size,
                              hipStream_t stream) {
    const float* x = (const float*)d_in[0];
    const float* W = (const float*)d_in[1];
    float* out = (float*)d_out;

    char* ws = (char*)d_ws;
    float* P  = (float*)ws;                               // 32 MB
    float* s0 = (float*)(ws + (size_t)32 * 1024 * 1024);  // 128 KB each
    float* s1 = s0 + S_ELEMS;

    dim3 r0g(NBC0 * NIC), r1g(NBC * NIC), rb(256);  // 1024 / 2048 blocks
    dim3 sg(B_TOT * 8), sb(256);                    // 512 blocks

    // iter 0: uniform c (1/32 folded into route1's inline squash as pre0)
    route0<<<r0g, rb, 0, stream>>>(x, W, P);
    reduce_s<<<sg, sb, 0, stream>>>(P, s0);
    // iter 1: c = softmax(u . squash(s0/32))
    route1<1><<<r1g, rb, 0, stream>>>(x, W, P, s0, nullptr, 1.0f / 32.0f);
    reduce_s<<<sg, sb, 0, stream>>>(P, s1);
    // iter 2: c = softmax(u . (squash(s0/32) + squash(s1)))
    route1<2><<<r1g, rb, 0, stream>>>(x, W, P, s0, s1, 1.0f / 32.0f);
    reduce_squash<<<sg, sb, 0, stream>>>(P, out);
}

// Round 13
// 185.370 us; speedup vs baseline: 1.0355x; 1.0355x over previous
//
#include <hip/hip_runtime.h>
#include <math.h>

// CapsLayer dynamic routing, MI355X fp32.
// x: [64, 2048, 8]  W: [2048, 32, 8, 16]  out: [64, 32, 16]
// Never materialize u_hat (256 MB); recompute per routing pass.
// R15: de-phase sibling blocks. R14 counters: FETCH ~= one fill per W line
// per pass, yet every block stalls ~45% — the 8 bc-siblings of an ic touch
// the SAME W tile at the SAME step, so the fill is MSHR-merged and ALL 8
// wait full miss latency every ii (no one ever hits a warm line). Fix:
// iterate tiles in order (ii + bc) & 7 — at step 0 the siblings fetch 8
// DIFFERENT tiles; from step 1 each reads a tile a sibling fetched one step
// earlier -> L2 hit for 7/8 iterations. Accumulation-order change only
// (within proven fp tolerance). Same rotation (stride 2) in route0.
// Everything else = R14: 6 dispatches, inline squash in route1 prologue,
// exclusive-write reduce (no atomics / no zeroing).
// Spill law (R3/R4/R6/R8): #pragma unroll 1 on ii is load-bearing.
// Tripwires: FETCH <= 80 MB (rotation must not thrash L2), absmax 0.00098,
// VGPR <= 64, route1 <= 50us.

#define B_TOT 64
#define I_TOT 2048
#define D_IN  8
#define NC    32
#define EV    16
#define OD    (NC*EV)      // 512 outputs per b
#define BC    8            // batch rows per block (softmax passes)
#define NBC   (B_TOT/BC)   // 8 b-chunks
#define BC0   16           // batch rows per block (pass-0 GEMM)
#define NBC0  (B_TOT/BC0)  // 4 b-chunks
#define ICH   8            // i's per block
#define NIC   (I_TOT/ICH)  // 256 i-chunks
#define S_ELEMS (B_TOT*OD) // 32768 floats = 128 KB per s-slice

__device__ __forceinline__ void fma4(float4& acc, float a, const float4& w) {
    acc.x = fmaf(a, w.x, acc.x);
    acc.y = fmaf(a, w.y, acc.y);
    acc.z = fmaf(a, w.z, acc.z);
    acc.w = fmaf(a, w.w, acc.w);
}

// ---- pass 0: c uniform. s0 = sum_i x[b,i,:] @ W[i] — a GEMM, no per-i u.
// BC0=16 rows/block: thread (eq,bh,n) folds wr[8] into 8 b-rows directly.
__global__ __launch_bounds__(256, 4)
void route0(const float* __restrict__ x, const float* __restrict__ W,
            float* __restrict__ P)
{
    __shared__ __align__(16) float xl[BC0 * ICH * D_IN];  // 4 KB

    const int t  = threadIdx.x;
    const int ic = blockIdx.x & (NIC - 1);   // 0..255 (blk%8==ic%8: XCD swz)
    const int bc = blockIdx.x >> 8;          // 0..3
    const int b0 = bc * BC0;
    const int i0 = ic * ICH;
    const int eq = t & 3;
    const int bh = (t >> 2) & 1;
    const int n  = t >> 3;

    // stage x[b0..b0+15][i0..i0+7][0..7] (4 KB): 256 float4, one per thread
    {
        const int row = t >> 4, f = (t & 15) * 4;
        *(float4*)&xl[row * (ICH * D_IN) + f] =
            *(const float4*)&x[((size_t)(b0 + row) * I_TOT + i0) * D_IN + f];
    }
    __syncthreads();

    float4 sacc[8];
    #pragma unroll
    for (int q = 0; q < 8; ++q) sacc[q] = make_float4(0.f, 0.f, 0.f, 0.f);

    const float* Wt = &W[(size_t)i0 * 4096 + n * 128 + eq * 4];

    // unroll 1 is load-bearing (spill law); iir de-phases the 4 bc-siblings
    #pragma unroll 1
    for (int ii = 0; ii < ICH; ++ii) {
        const int iir = (ii + bc * 2) & 7;
        float4 wr[8];
        #pragma unroll
        for (int d = 0; d < 8; ++d)
            wr[d] = *(const float4*)&Wt[iir * 4096 + d * 16];

        #pragma unroll
        for (int q = 0; q < 8; ++q) {
            const int bl = bh * 8 + q;
            float4 xa = *(float4*)&xl[bl * (ICH * D_IN) + iir * 8];
            float4 xb = *(float4*)&xl[bl * (ICH * D_IN) + iir * 8 + 4];
            fma4(sacc[q], xa.x, wr[0]); fma4(sacc[q], xa.y, wr[1]);
            fma4(sacc[q], xa.z, wr[2]); fma4(sacc[q], xa.w, wr[3]);
            fma4(sacc[q], xb.x, wr[4]); fma4(sacc[q], xb.y, wr[5]);
            fma4(sacc[q], xb.z, wr[6]); fma4(sacc[q], xb.w, wr[7]);
        }
    }

    #pragma unroll
    for (int q = 0; q < 8; ++q)
        *(float4*)&P[((size_t)ic * B_TOT + b0 + bh * 8 + q) * OD + n * EV + eq * 4] = sacc[q];
}

// ---- passes 1/2: c = softmax_n(u . v). v is reconstructed in the prologue
// from the raw reduce sums: NS=1: v = squash(s0*pre0); NS=2: v = squash(s0*
// pre0) + squash(s1)  (iter-2 logits u.v0 + u.v1 = u.(v0+v1), dot linearity).
template <int NS>
__global__ __launch_bounds__(256, 4)
void route1(const float* __restrict__ x, const float* __restrict__ W,
            float* __restrict__ P, const float* __restrict__ s0,
            const float* __restrict__ s1, float pre0)
{
    __shared__ __align__(16) float xl[BC * ICH * D_IN];   // 2 KB
    __shared__ float wsum[2][4][BC];                      // 256 B (ii-dbuf)

    const int t  = threadIdx.x;
    const int ic = blockIdx.x & (NIC - 1);   // 0..255 (blk%8==ic%8: XCD swz)
    const int bc = blockIdx.x >> 8;          // 0..7
    const int b0 = bc * BC;
    const int i0 = ic * ICH;
    const int eq = t & 3;          // e quarter (4 e's)
    const int bh = (t >> 2) & 1;   // b half (4 b's each)
    const int n  = t >> 3;         // capsule 0..31
    const int w  = t >> 6;         // wave 0..3

    if (t < 128) {
        const int row = t >> 4, f = (t & 15) * 4;
        *(float4*)&xl[row * (ICH * D_IN) + f] =
            *(const float4*)&x[((size_t)(b0 + row) * I_TOT + i0) * D_IN + f];
    }

    // ---- inline squash: vr[q] = v[b0+bh*4+q][n][eq*4..+3] ----
    // norm over the 16 e's of (b,n): in-thread dot of 4 + shfl over eq bits.
    float4 vr[4];
    #pragma unroll
    for (int q = 0; q < 4; ++q) {
        const size_t off = (size_t)(b0 + bh * 4 + q) * OD + n * EV + eq * 4;
        float4 t0 = *(const float4*)&s0[off];
        t0.x *= pre0; t0.y *= pre0; t0.z *= pre0; t0.w *= pre0;
        float q2 = t0.x*t0.x + t0.y*t0.y + t0.z*t0.z + t0.w*t0.w;
        q2 += __shfl_xor(q2, 1, 64);
        q2 += __shfl_xor(q2, 2, 64);
        float sc = q2 / ((1.0f + q2) * sqrtf(q2));
        float4 v = make_float4(t0.x*sc, t0.y*sc, t0.z*sc, t0.w*sc);
        if (NS == 2) {
            float4 t1 = *(const float4*)&s1[off];
            float r2 = t1.x*t1.x + t1.y*t1.y + t1.z*t1.z + t1.w*t1.w;
            r2 += __shfl_xor(r2, 1, 64);
            r2 += __shfl_xor(r2, 2, 64);
            float sc1 = r2 / ((1.0f + r2) * sqrtf(r2));
            v.x = fmaf(t1.x, sc1, v.x); v.y = fmaf(t1.y, sc1, v.y);
            v.z = fmaf(t1.z, sc1, v.z); v.w = fmaf(t1.w, sc1, v.w);
        }
        vr[q] = v;
    }
    __syncthreads();

    float4 sacc[4];
    #pragma unroll
    for (int q = 0; q < 4; ++q) sacc[q] = make_float4(0.f, 0.f, 0.f, 0.f);

    const float* Wt = &W[(size_t)i0 * 4096 + n * 128 + eq * 4];

    // unroll 1 is load-bearing (spill law: R3/R4 hoist -> 1.1 GB scratch).
    // iir = (ii + bc) & 7 de-phases the 8 bc-siblings of this ic: step 0
    // fetches 8 different tiles in parallel; steps 1..7 hit L2 lines a
    // sibling fetched one step earlier (miss-wait -> hit for 7/8 iters).
    #pragma unroll 1
    for (int ii = 0; ii < ICH; ++ii) {
        const int iir = (ii + bc) & 7;
        float4 wr[8];
        #pragma unroll
        for (int d = 0; d < 8; ++d)
            wr[d] = *(const float4*)&Wt[iir * 4096 + d * 16];

        float4 u[4];
        #pragma unroll
        for (int q = 0; q < 4; ++q) {
            const int bl = bh * 4 + q;
            float4 xa = *(float4*)&xl[bl * (ICH * D_IN) + iir * 8];
            float4 xb = *(float4*)&xl[bl * (ICH * D_IN) + iir * 8 + 4];
            float4 uu = make_float4(0.f, 0.f, 0.f, 0.f);
            fma4(uu, xa.x, wr[0]); fma4(uu, xa.y, wr[1]);
            fma4(uu, xa.z, wr[2]); fma4(uu, xa.w, wr[3]);
            fma4(uu, xb.x, wr[4]); fma4(uu, xb.y, wr[5]);
            fma4(uu, xb.z, wr[6]); fma4(uu, xb.w, wr[7]);
            u[q] = uu;
        }

        float a[4];
        #pragma unroll
        for (int q = 0; q < 4; ++q) {
            float ap = u[q].x * vr[q].x + u[q].y * vr[q].y
                     + u[q].z * vr[q].z + u[q].w * vr[q].w;
            ap += __shfl_xor(ap, 1, 64);
            ap += __shfl_xor(ap, 2, 64);
            a[q] = ap;
        }
        float e[4], p[4];
        #pragma unroll
        for (int q = 0; q < 4; ++q) {
            e[q] = __expf(a[q]);
            float pp = e[q];
            pp += __shfl_xor(pp, 8, 64);
            pp += __shfl_xor(pp, 16, 64);
            pp += __shfl_xor(pp, 32, 64);
            p[q] = pp;
        }
        if (eq == 0) {
            #pragma unroll
            for (int q = 0; q < 4; ++q)
                wsum[ii & 1][w][bh * 4 + q] = p[q];
        }
        __syncthreads();
        #pragma unroll
        for (int q = 0; q < 4; ++q) {
            const int bl = bh * 4 + q;
            float s = wsum[ii & 1][0][bl] + wsum[ii & 1][1][bl]
                    + wsum[ii & 1][2][bl] + wsum[ii & 1][3][bl];
            float c = __fdividef(e[q], s);
            fma4(sacc[q], c, u[q]);
        }
    }

    #pragma unroll
    for (int q = 0; q < 4; ++q)
        *(float4*)&P[((size_t)ic * B_TOT + b0 + bh * 4 + q) * OD + n * EV + eq * 4] = sacc[q];
}

// ---- reduce P over 256 i-chunks into s[b][o]. 512 blocks (b x 8 o-slices),
// exclusive writes (no atomics, no zeroing). 256 thr = 64 o x 4 ic-quarters.
__global__ __launch_bounds__(256, 4)
void reduce_s(const float* __restrict__ P, float* __restrict__ s)
{
    __shared__ float red[256];
    const int b   = blockIdx.x >> 3;
    const int oq  = blockIdx.x & 7;
    const int t   = threadIdx.x;
    const int o   = oq * 64 + (t & 63);
    const int icq = t >> 6;                       // 0..3
    const size_t stride = (size_t)B_TOT * OD;

    float acc = 0.f;
    size_t base = ((size_t)(icq * 64) * B_TOT + b) * OD + o;
    #pragma unroll 8
    for (int k = 0; k < 64; ++k) acc += P[base + (size_t)k * stride];
    red[t] = acc;
    __syncthreads();
    if (t < 64)
        s[(size_t)b * OD + o] = red[t] + red[t + 64] + red[t + 128] + red[t + 192];
}

// ---- final: reduce P over ic then squash, straight into out. 512 blocks.
__global__ __launch_bounds__(256, 4)
void reduce_squash(const float* __restrict__ P, float* __restrict__ dst)
{
    __shared__ float red[256];
    const int b   = blockIdx.x >> 3;
    const int oq  = blockIdx.x & 7;
    const int t   = threadIdx.x;
    const int o   = oq * 64 + (t & 63);
    const int icq = t >> 6;
    const size_t stride = (size_t)B_TOT * OD;

    float acc = 0.f;
    size_t base = ((size_t)(icq * 64) * B_TOT + b) * OD + o;
    #pragma unroll 8
    for (int k = 0; k < 64; ++k) acc += P[base + (size_t)k * stride];
    red[t] = acc;
    __syncthreads();

    if (t < 64) {
        float v = red[t] + red[t + 64] + red[t + 128] + red[t + 192];
        float q2 = v * v;
        q2 += __shfl_xor(q2, 1, 64);
        q2 += __shfl_xor(q2, 2, 64);
        q2 += __shfl_xor(q2, 4, 64);
        q2 += __shfl_xor(q2, 8, 64);
        float sc = q2 / ((1.0f + q2) * sqrtf(q2));
        dst[(size_t)b * OD + o] = v * sc;
    }
}

extern "C" void kernel_launch(void* const* d_in, const int* in_sizes, int n_in,
                              void* d_out, int out_size, void* d_ws, size_t ws_size,
                              hipStream_t stream) {
    const float* x = (const float*)d_in[0];
    const float* W = (const float*)d_in[1];
    float* out = (float*)d_out;

    char* ws = (char*)d_ws;
    float* P  = (float*)ws;                               // 32 MB
    float* s0 = (float*)(ws + (size_t)32 * 1024 * 1024);  // 128 KB each
    float* s1 = s0 + S_ELEMS;

    dim3 r0g(NBC0 * NIC), r1g(NBC * NIC), rb(256);  // 1024 / 2048 blocks
    dim3 sg(B_TOT * 8), sb(256);                    // 512 blocks

    // iter 0: uniform c (1/32 folded into route1's inline squash as pre0)
    route0<<<r0g, rb, 0, stream>>>(x, W, P);
    reduce_s<<<sg, sb, 0, stream>>>(P, s0);
    // iter 1: c = softmax(u . squash(s0/32))
    route1<1><<<r1g, rb, 0, stream>>>(x, W, P, s0, nullptr, 1.0f / 32.0f);
    reduce_s<<<sg, sb, 0, stream>>>(P, s1);
    // iter 2: c = softmax(u . (squash(s0/32) + squash(s1)))
    route1<2><<<r1g, rb, 0, stream>>>(x, W, P, s0, s1, 1.0f / 32.0f);
    reduce_squash<<<sg, sb, 0, stream>>>(P, out);
}